// Round 1
// baseline (259.425 us; speedup 1.0000x reference)
//
#include <hip/hip_runtime.h>

// Problem constants
#define BSZ 4
#define CH 64
#define IH 128
#define IW 128
#define PN 63      // number of gaussians
#define TS 16      // spatial tile
#define HALO 2
#define TSH (TS + 2*HALO)   // 20
#define NTILES 256          // 4 images * 8*8 tiles
#define WRAD 5              // gaussian window radius (11 taps)

// ---------------------------------------------------------------------------
// kA: c0 = conv5x5(edge-pad(255*x), f0) + b0  (1 -> 64 ch)
//     a0 = sum_p w0[c,p] * exp(-(c0-mean_p)^2/200)
//     g0 = sum_p w0[c,p] * exp(...) * (c0-mean_p)/(-100)
// grid: (NTILES, 4 channel groups of 16), block 256 = 16x16 pixels
// ---------------------------------------------------------------------------
__global__ __launch_bounds__(256) void kA(const float* __restrict__ x,
                                          const float* __restrict__ f0,
                                          const float* __restrict__ b0,
                                          const float* __restrict__ w0,
                                          float* __restrict__ a0,
                                          float* __restrict__ g0) {
    __shared__ float xs[TSH][TSH];
    __shared__ float f0s[16][25];
    __shared__ float w0s[16][PN];

    const int tile = blockIdx.x;
    const int cg   = blockIdx.y * 16;
    const int b    = tile >> 6;          // 64 tiles per image
    const int t    = tile & 63;
    const int h0   = (t >> 3) * TS;
    const int w0p  = (t & 7) * TS;
    const int tid  = threadIdx.x;
    const int lx   = tid & 15;
    const int ly   = tid >> 4;

    // stage x tile (edge clamp), pre-scale by 255
    for (int i = tid; i < TSH * TSH; i += 256) {
        int iy = i / TSH, ix = i % TSH;
        int gy = min(max(h0 + iy - HALO, 0), IH - 1);
        int gx = min(max(w0p + ix - HALO, 0), IW - 1);
        xs[iy][ix] = x[((size_t)b * IH + gy) * IW + gx] * 255.0f;
    }
    for (int i = tid; i < 16 * 25; i += 256)
        f0s[i / 25][i % 25] = f0[(size_t)(cg + i / 25) * 25 + (i % 25)];
    for (int i = tid; i < 16 * PN; i += 256)
        w0s[i / PN][i % PN] = w0[(size_t)(cg + i / PN) * PN + (i % PN)];
    __syncthreads();

    const int gh = h0 + ly, gw = w0p + lx;

    for (int cc = 0; cc < 16; ++cc) {
        const int c = cg + cc;
        float acc = b0[c];
#pragma unroll
        for (int u = 0; u < 5; ++u)
#pragma unroll
            for (int v = 0; v < 5; ++v)
                acc += xs[ly + u][lx + v] * f0s[cc][u * 5 + v];

        // windowed gaussian-mixture activation (value + gradient)
        const float vv = acc;
        int pc = (int)floorf((vv + 310.0f) * 0.1f + 0.5f);
        pc = min(max(pc, 0), PN - 1);
        float accv = 0.0f, accg = 0.0f;
#pragma unroll
        for (int j = -WRAD; j <= WRAD; ++j) {
            int p  = pc + j;
            int pi = min(max(p, 0), PN - 1);
            float wgt = (p == pi) ? w0s[cc][pi] : 0.0f;   // mask, don't clamp
            float dd = vv - (-310.0f + 10.0f * (float)pi);
            float g  = __expf(dd * dd * -0.005f);
            accv += wgt * g;
            accg += wgt * g * dd;
        }
        const size_t idx = ((((size_t)b * CH + c) * IH + gh)) * IW + gw;
        a0[idx] = accv;
        g0[idx] = accg * -0.01f;
    }
}

// ---------------------------------------------------------------------------
// kB: c1 = conv5x5(edge-pad(a0), f1) + b1  (64 -> 1 ch), a1 = act(c1, w1)
// grid: NTILES, block 256
// ---------------------------------------------------------------------------
__global__ __launch_bounds__(256) void kB(const float* __restrict__ a0,
                                          const float* __restrict__ f1,
                                          const float* __restrict__ b1,
                                          const float* __restrict__ w1,
                                          float* __restrict__ a1) {
    __shared__ float as[TSH][TSH];
    __shared__ float f1s[CH][25];
    __shared__ float w1s[PN];

    const int tile = blockIdx.x;
    const int b    = tile >> 6;
    const int t    = tile & 63;
    const int h0   = (t >> 3) * TS;
    const int w0p  = (t & 7) * TS;
    const int tid  = threadIdx.x;
    const int lx   = tid & 15;
    const int ly   = tid >> 4;

    for (int i = tid; i < CH * 25; i += 256) f1s[i / 25][i % 25] = f1[i];
    if (tid < PN) w1s[tid] = w1[tid];

    float acc = b1[0];
    const int gh = h0 + ly, gw = w0p + lx;

    for (int c = 0; c < CH; ++c) {
        __syncthreads();
        for (int i = tid; i < TSH * TSH; i += 256) {
            int iy = i / TSH, ix = i % TSH;
            int gy = min(max(h0 + iy - HALO, 0), IH - 1);
            int gx = min(max(w0p + ix - HALO, 0), IW - 1);
            as[iy][ix] = a0[(((size_t)b * CH + c) * IH + gy) * IW + gx];
        }
        __syncthreads();
#pragma unroll
        for (int u = 0; u < 5; ++u)
#pragma unroll
            for (int v = 0; v < 5; ++v)
                acc += as[ly + u][lx + v] * f1s[c][u * 5 + v];
    }

    const float vv = acc;
    int pc = (int)floorf((vv + 310.0f) * 0.1f + 0.5f);
    pc = min(max(pc, 0), PN - 1);
    float accv = 0.0f;
#pragma unroll
    for (int j = -WRAD; j <= WRAD; ++j) {
        int p  = pc + j;
        int pi = min(max(p, 0), PN - 1);
        float wgt = (p == pi) ? w1s[pi] : 0.0f;
        float dd = vv - (-310.0f + 10.0f * (float)pi);
        accv += wgt * __expf(dd * dd * -0.005f);
    }
    a1[((size_t)b * IH + gh) * IW + gw] = accv;
}

// ---------------------------------------------------------------------------
// kC: d1[b,c,h,w] = sum_{u,v} f1[c,u,v] * a1[b, h+2-u, w+2-v]  (zero pad)
//     d[b,c,h,w]  = d1 * g0[b,c,h,w]     (written in place over g0)
// grid: (NTILES, 4 channel groups of 16), block 256
// ---------------------------------------------------------------------------
__global__ __launch_bounds__(256) void kC(const float* __restrict__ a1,
                                          const float* __restrict__ f1,
                                          const float* __restrict__ g0,
                                          float* __restrict__ dbuf) {
    __shared__ float as[TSH][TSH];
    __shared__ float f1s[16][25];

    const int tile = blockIdx.x;
    const int cg   = blockIdx.y * 16;
    const int b    = tile >> 6;
    const int t    = tile & 63;
    const int h0   = (t >> 3) * TS;
    const int w0p  = (t & 7) * TS;
    const int tid  = threadIdx.x;
    const int lx   = tid & 15;
    const int ly   = tid >> 4;

    for (int i = tid; i < TSH * TSH; i += 256) {
        int iy = i / TSH, ix = i % TSH;
        int gy = h0 + iy - HALO, gx = w0p + ix - HALO;
        float v = 0.0f;
        if (gy >= 0 && gy < IH && gx >= 0 && gx < IW)
            v = a1[((size_t)b * IH + gy) * IW + gx];
        as[iy][ix] = v;
    }
    for (int i = tid; i < 16 * 25; i += 256)
        f1s[i / 25][i % 25] = f1[(size_t)(cg + i / 25) * 25 + (i % 25)];
    __syncthreads();

    const int gh = h0 + ly, gw = w0p + lx;

    for (int cc = 0; cc < 16; ++cc) {
        const int c = cg + cc;
        float acc = 0.0f;
#pragma unroll
        for (int u = 0; u < 5; ++u)
#pragma unroll
            for (int v = 0; v < 5; ++v)
                acc += f1s[cc][u * 5 + v] * as[ly + 4 - u][lx + 4 - v];
        const size_t idx = (((size_t)b * CH + c) * IH + gh) * IW + gw;
        dbuf[idx] = acc * g0[idx];
    }
}

// ---------------------------------------------------------------------------
// kD: d3[b,h,w] = sum_c sum_{u,v} f0[c,u,v] * d[b,c,h+2-u,w+2-v] (zero pad)
//     out = x - d3/255 - exp(lam)*(x - y)
// grid: NTILES, block 256
// ---------------------------------------------------------------------------
__global__ __launch_bounds__(256) void kD(const float* __restrict__ dbuf,
                                          const float* __restrict__ f0,
                                          const float* __restrict__ x,
                                          const float* __restrict__ y,
                                          const float* __restrict__ lam_param,
                                          float* __restrict__ out) {
    __shared__ float ds[TSH][TSH];
    __shared__ float f0s[CH][25];

    const int tile = blockIdx.x;
    const int b    = tile >> 6;
    const int t    = tile & 63;
    const int h0   = (t >> 3) * TS;
    const int w0p  = (t & 7) * TS;
    const int tid  = threadIdx.x;
    const int lx   = tid & 15;
    const int ly   = tid >> 4;

    for (int i = tid; i < CH * 25; i += 256) f0s[i / 25][i % 25] = f0[i];

    float acc = 0.0f;
    const int gh = h0 + ly, gw = w0p + lx;

    for (int c = 0; c < CH; ++c) {
        __syncthreads();
        for (int i = tid; i < TSH * TSH; i += 256) {
            int iy = i / TSH, ix = i % TSH;
            int gy = h0 + iy - HALO, gx = w0p + ix - HALO;
            float v = 0.0f;
            if (gy >= 0 && gy < IH && gx >= 0 && gx < IW)
                v = dbuf[(((size_t)b * CH + c) * IH + gy) * IW + gx];
            ds[iy][ix] = v;
        }
        __syncthreads();
#pragma unroll
        for (int u = 0; u < 5; ++u)
#pragma unroll
            for (int v = 0; v < 5; ++v)
                acc += f0s[c][u * 5 + v] * ds[ly + 4 - u][lx + 4 - v];
    }

    const float elam = __expf(lam_param[0]);
    const size_t pidx = ((size_t)b * IH + gh) * IW + gw;
    const float xv = x[pidx], yv = y[pidx];
    out[pidx] = xv - acc * (1.0f / 255.0f) - elam * (xv - yv);
}

// ---------------------------------------------------------------------------
extern "C" void kernel_launch(void* const* d_in, const int* in_sizes, int n_in,
                              void* d_out, int out_size, void* d_ws, size_t ws_size,
                              hipStream_t stream) {
    const float* x   = (const float*)d_in[0];
    const float* y   = (const float*)d_in[1];
    // d_in[2] = lam (ignored by reference)
    const float* f0  = (const float*)d_in[3];
    const float* b0  = (const float*)d_in[4];
    const float* f1  = (const float*)d_in[5];
    const float* b1  = (const float*)d_in[6];
    const float* w0  = (const float*)d_in[7];
    const float* w1  = (const float*)d_in[8];
    const float* lam = (const float*)d_in[9];
    float* out = (float*)d_out;

    const size_t nch = (size_t)BSZ * CH * IH * IW;   // 4.19M floats
    float* a0   = (float*)d_ws;
    float* g0   = a0 + nch;
    float* a1   = g0 + nch;
    float* dbuf = g0;   // kC reads g0[idx], writes same idx -> in-place OK

    kA<<<dim3(NTILES, 4), 256, 0, stream>>>(x, f0, b0, w0, a0, g0);
    kB<<<NTILES, 256, 0, stream>>>(a0, f1, b1, w1, a1);
    kC<<<dim3(NTILES, 4), 256, 0, stream>>>(a1, f1, g0, dbuf);
    kD<<<NTILES, 256, 0, stream>>>(dbuf, f0, x, y, lam, out);
}

// Round 2
// 174.162 us; speedup vs baseline: 1.4896x; 1.4896x over previous
//
#include <hip/hip_runtime.h>

// Problem constants
#define BSZ 4
#define CH 64
#define IH 128
#define IW 128
#define PN 63      // number of gaussians
#define TS 16      // spatial tile
#define HALO 2
#define TSH (TS + 2*HALO)   // 20
#define NTILES 256          // 4 images * 8*8 tiles
#define NPIX (BSZ*IH*IW)    // 65536
#define WRAD 5              // gaussian window radius (11 taps)

// ---------------------------------------------------------------------------
// kA: c0 = conv5x5(edge-pad(255*x), f0) + b0  (1 -> 64 ch)
//     a0 = sum_p w0[c,p] * exp(-(c0-mean_p)^2/200)
//     g0 = sum_p w0[c,p] * exp(...) * (c0-mean_p)/(-100)
// grid: (NTILES, 4 channel groups of 16), block 256 = 16x16 pixels
// ---------------------------------------------------------------------------
__global__ __launch_bounds__(256) void kA(const float* __restrict__ x,
                                          const float* __restrict__ f0,
                                          const float* __restrict__ b0,
                                          const float* __restrict__ w0,
                                          float* __restrict__ a0,
                                          float* __restrict__ g0) {
    __shared__ float xs[TSH][TSH];
    __shared__ float f0s[16][25];
    __shared__ float w0s[16][PN];

    const int tile = blockIdx.x;
    const int cg   = blockIdx.y * 16;
    const int b    = tile >> 6;          // 64 tiles per image
    const int t    = tile & 63;
    const int h0   = (t >> 3) * TS;
    const int w0p  = (t & 7) * TS;
    const int tid  = threadIdx.x;
    const int lx   = tid & 15;
    const int ly   = tid >> 4;

    for (int i = tid; i < TSH * TSH; i += 256) {
        int iy = i / TSH, ix = i % TSH;
        int gy = min(max(h0 + iy - HALO, 0), IH - 1);
        int gx = min(max(w0p + ix - HALO, 0), IW - 1);
        xs[iy][ix] = x[((size_t)b * IH + gy) * IW + gx] * 255.0f;
    }
    for (int i = tid; i < 16 * 25; i += 256)
        f0s[i / 25][i % 25] = f0[(size_t)(cg + i / 25) * 25 + (i % 25)];
    for (int i = tid; i < 16 * PN; i += 256)
        w0s[i / PN][i % PN] = w0[(size_t)(cg + i / PN) * PN + (i % PN)];
    __syncthreads();

    const int gh = h0 + ly, gw = w0p + lx;

    for (int cc = 0; cc < 16; ++cc) {
        const int c = cg + cc;
        float acc = b0[c];
#pragma unroll
        for (int u = 0; u < 5; ++u)
#pragma unroll
            for (int v = 0; v < 5; ++v)
                acc += xs[ly + u][lx + v] * f0s[cc][u * 5 + v];

        const float vv = acc;
        int pc = (int)floorf((vv + 310.0f) * 0.1f + 0.5f);
        pc = min(max(pc, 0), PN - 1);
        float accv = 0.0f, accg = 0.0f;
#pragma unroll
        for (int j = -WRAD; j <= WRAD; ++j) {
            int p  = pc + j;
            int pi = min(max(p, 0), PN - 1);
            float wgt = (p == pi) ? w0s[cc][pi] : 0.0f;   // mask, don't clamp
            float dd = vv - (-310.0f + 10.0f * (float)pi);
            float g  = __expf(dd * dd * -0.005f);
            accv += wgt * g;
            accg += wgt * g * dd;
        }
        const size_t idx = ((((size_t)b * CH + c) * IH + gh)) * IW + gw;
        a0[idx] = accv;
        g0[idx] = accg * -0.01f;
    }
}

// ---------------------------------------------------------------------------
// kB1: partial c1 over a 16-channel group (edge-pad conv, 64->1)
// grid: (NTILES, 4), block 256. One barrier total.
// ---------------------------------------------------------------------------
__global__ __launch_bounds__(256) void kB1(const float* __restrict__ a0,
                                           const float* __restrict__ f1,
                                           float* __restrict__ c1p) {
    __shared__ float as[16][TSH * TSH];   // 25.6 KB
    __shared__ float f1s[16][25];

    const int tile = blockIdx.x;
    const int cgi  = blockIdx.y;
    const int cg   = cgi * 16;
    const int b    = tile >> 6;
    const int t    = tile & 63;
    const int h0   = (t >> 3) * TS;
    const int w0p  = (t & 7) * TS;
    const int tid  = threadIdx.x;
    const int lx   = tid & 15;
    const int ly   = tid >> 4;

    for (int i = tid; i < 16 * TSH * TSH; i += 256) {
        int cc = i / (TSH * TSH);
        int r  = i - cc * (TSH * TSH);
        int iy = r / TSH, ix = r - iy * TSH;
        int gy = min(max(h0 + iy - HALO, 0), IH - 1);
        int gx = min(max(w0p + ix - HALO, 0), IW - 1);
        as[cc][r] = a0[(((size_t)b * CH + cg + cc) * IH + gy) * IW + gx];
    }
    for (int i = tid; i < 16 * 25; i += 256)
        f1s[i / 25][i % 25] = f1[(size_t)(cg + i / 25) * 25 + (i % 25)];
    __syncthreads();

    float acc = 0.0f;
#pragma unroll 4
    for (int cc = 0; cc < 16; ++cc) {
#pragma unroll
        for (int u = 0; u < 5; ++u)
#pragma unroll
            for (int v = 0; v < 5; ++v)
                acc += as[cc][(ly + u) * TSH + lx + v] * f1s[cc][u * 5 + v];
    }

    const int gh = h0 + ly, gw = w0p + lx;
    c1p[(size_t)cgi * NPIX + ((size_t)b * IH + gh) * IW + gw] = acc;
}

// ---------------------------------------------------------------------------
// kB2: c1 = b1 + sum partials; a1 = act(c1, w1)
// ---------------------------------------------------------------------------
__global__ __launch_bounds__(256) void kB2(const float* __restrict__ c1p,
                                           const float* __restrict__ b1,
                                           const float* __restrict__ w1,
                                           float* __restrict__ a1) {
    __shared__ float w1s[PN];
    const int tid = threadIdx.x;
    if (tid < PN) w1s[tid] = w1[tid];
    __syncthreads();

    const int pid = blockIdx.x * 256 + tid;
    float vv = b1[0] + c1p[pid] + c1p[NPIX + pid] + c1p[2 * NPIX + pid] + c1p[3 * NPIX + pid];

    int pc = (int)floorf((vv + 310.0f) * 0.1f + 0.5f);
    pc = min(max(pc, 0), PN - 1);
    float accv = 0.0f;
#pragma unroll
    for (int j = -WRAD; j <= WRAD; ++j) {
        int p  = pc + j;
        int pi = min(max(p, 0), PN - 1);
        float wgt = (p == pi) ? w1s[pi] : 0.0f;
        float dd = vv - (-310.0f + 10.0f * (float)pi);
        accv += wgt * __expf(dd * dd * -0.005f);
    }
    a1[pid] = accv;
}

// ---------------------------------------------------------------------------
// kC: d1[b,c,h,w] = sum_{u,v} f1[c,u,v] * a1[b, h+2-u, w+2-v]  (zero pad)
//     d[b,c,h,w]  = d1 * g0[b,c,h,w]     (written in place over g0)
// grid: (NTILES, 4 channel groups of 16), block 256
// ---------------------------------------------------------------------------
__global__ __launch_bounds__(256) void kC(const float* __restrict__ a1,
                                          const float* __restrict__ f1,
                                          const float* __restrict__ g0,
                                          float* __restrict__ dbuf) {
    __shared__ float as[TSH][TSH];
    __shared__ float f1s[16][25];

    const int tile = blockIdx.x;
    const int cg   = blockIdx.y * 16;
    const int b    = tile >> 6;
    const int t    = tile & 63;
    const int h0   = (t >> 3) * TS;
    const int w0p  = (t & 7) * TS;
    const int tid  = threadIdx.x;
    const int lx   = tid & 15;
    const int ly   = tid >> 4;

    for (int i = tid; i < TSH * TSH; i += 256) {
        int iy = i / TSH, ix = i % TSH;
        int gy = h0 + iy - HALO, gx = w0p + ix - HALO;
        float v = 0.0f;
        if (gy >= 0 && gy < IH && gx >= 0 && gx < IW)
            v = a1[((size_t)b * IH + gy) * IW + gx];
        as[iy][ix] = v;
    }
    for (int i = tid; i < 16 * 25; i += 256)
        f1s[i / 25][i % 25] = f1[(size_t)(cg + i / 25) * 25 + (i % 25)];
    __syncthreads();

    const int gh = h0 + ly, gw = w0p + lx;

    for (int cc = 0; cc < 16; ++cc) {
        const int c = cg + cc;
        float acc = 0.0f;
#pragma unroll
        for (int u = 0; u < 5; ++u)
#pragma unroll
            for (int v = 0; v < 5; ++v)
                acc += f1s[cc][u * 5 + v] * as[ly + 4 - u][lx + 4 - v];
        const size_t idx = (((size_t)b * CH + c) * IH + gh) * IW + gw;
        dbuf[idx] = acc * g0[idx];
    }
}

// ---------------------------------------------------------------------------
// kD1: partial d3 over a 16-channel group (zero-pad full-corr, 64->1)
// grid: (NTILES, 4), block 256
// ---------------------------------------------------------------------------
__global__ __launch_bounds__(256) void kD1(const float* __restrict__ dbuf,
                                           const float* __restrict__ f0,
                                           float* __restrict__ d3p) {
    __shared__ float ds[16][TSH * TSH];
    __shared__ float f0s[16][25];

    const int tile = blockIdx.x;
    const int cgi  = blockIdx.y;
    const int cg   = cgi * 16;
    const int b    = tile >> 6;
    const int t    = tile & 63;
    const int h0   = (t >> 3) * TS;
    const int w0p  = (t & 7) * TS;
    const int tid  = threadIdx.x;
    const int lx   = tid & 15;
    const int ly   = tid >> 4;

    for (int i = tid; i < 16 * TSH * TSH; i += 256) {
        int cc = i / (TSH * TSH);
        int r  = i - cc * (TSH * TSH);
        int iy = r / TSH, ix = r - iy * TSH;
        int gy = h0 + iy - HALO, gx = w0p + ix - HALO;
        float v = 0.0f;
        if (gy >= 0 && gy < IH && gx >= 0 && gx < IW)
            v = dbuf[(((size_t)b * CH + cg + cc) * IH + gy) * IW + gx];
        ds[cc][r] = v;
    }
    for (int i = tid; i < 16 * 25; i += 256)
        f0s[i / 25][i % 25] = f0[(size_t)(cg + i / 25) * 25 + (i % 25)];
    __syncthreads();

    float acc = 0.0f;
#pragma unroll 4
    for (int cc = 0; cc < 16; ++cc) {
#pragma unroll
        for (int u = 0; u < 5; ++u)
#pragma unroll
            for (int v = 0; v < 5; ++v)
                acc += f0s[cc][u * 5 + v] * ds[cc][(ly + 4 - u) * TSH + lx + 4 - v];
    }

    const int gh = h0 + ly, gw = w0p + lx;
    d3p[(size_t)cgi * NPIX + ((size_t)b * IH + gh) * IW + gw] = acc;
}

// ---------------------------------------------------------------------------
// kD2: out = x - (sum d3p)/255 - exp(lam)*(x-y)
// ---------------------------------------------------------------------------
__global__ __launch_bounds__(256) void kD2(const float* __restrict__ d3p,
                                           const float* __restrict__ x,
                                           const float* __restrict__ y,
                                           const float* __restrict__ lam_param,
                                           float* __restrict__ out) {
    const int pid = blockIdx.x * 256 + threadIdx.x;
    float d3 = d3p[pid] + d3p[NPIX + pid] + d3p[2 * NPIX + pid] + d3p[3 * NPIX + pid];
    const float elam = __expf(lam_param[0]);
    const float xv = x[pid], yv = y[pid];
    out[pid] = xv - d3 * (1.0f / 255.0f) - elam * (xv - yv);
}

// ---------------------------------------------------------------------------
extern "C" void kernel_launch(void* const* d_in, const int* in_sizes, int n_in,
                              void* d_out, int out_size, void* d_ws, size_t ws_size,
                              hipStream_t stream) {
    const float* x   = (const float*)d_in[0];
    const float* y   = (const float*)d_in[1];
    // d_in[2] = lam (ignored by reference)
    const float* f0  = (const float*)d_in[3];
    const float* b0  = (const float*)d_in[4];
    const float* f1  = (const float*)d_in[5];
    const float* b1  = (const float*)d_in[6];
    const float* w0  = (const float*)d_in[7];
    const float* w1  = (const float*)d_in[8];
    const float* lam = (const float*)d_in[9];
    float* out = (float*)d_out;

    const size_t nch = (size_t)BSZ * CH * IH * IW;   // 4.19M floats
    float* a0   = (float*)d_ws;          // dead after kB1
    float* g0   = a0 + nch;              // dbuf written in-place by kC
    float* a1   = g0 + nch;              // NPIX
    float* c1p  = a1 + NPIX;             // 4*NPIX partials (kB1 -> kB2)
    float* dbuf = g0;
    float* d3p  = a0;                    // reuse a0's space (kD1 -> kD2)

    kA <<<dim3(NTILES, 4), 256, 0, stream>>>(x, f0, b0, w0, a0, g0);
    kB1<<<dim3(NTILES, 4), 256, 0, stream>>>(a0, f1, c1p);
    kB2<<<NPIX / 256, 256, 0, stream>>>(c1p, b1, w1, a1);
    kC <<<dim3(NTILES, 4), 256, 0, stream>>>(a1, f1, g0, dbuf);
    kD1<<<dim3(NTILES, 4), 256, 0, stream>>>(dbuf, f0, d3p);
    kD2<<<NPIX / 256, 256, 0, stream>>>(d3p, x, y, lam, out);
}

// Round 3
// 154.880 us; speedup vs baseline: 1.6750x; 1.1245x over previous
//
#include <hip/hip_runtime.h>

// Problem constants
#define BSZ 4
#define CH 64
#define IH 128
#define IW 128
#define PN 63          // number of gaussians
#define TLS 32         // spatial tile (32x32 outputs per block)
#define HALO 2
#define TLH 36         // 32 + 2*2
#define NT 64          // 4 images * 4*4 tiles
#define CG 8           // channels per group
#define NG 8           // channel groups
#define NPIX (BSZ*IH*IW)   // 65536

// Gaussian-mixture activation, 11-tap window (exp(-d^2/200) < 3e-7 beyond |d|=55)
__device__ __forceinline__ void act_vg(float vv, const float* __restrict__ wrow,
                                       float& av, float& ag) {
    int pc = (int)floorf((vv + 310.0f) * 0.1f + 0.5f);
    pc = min(max(pc, 0), PN - 1);
    float accv = 0.0f, accg = 0.0f;
#pragma unroll
    for (int j = -5; j <= 5; ++j) {
        int p  = pc + j;
        int pi = min(max(p, 0), PN - 1);
        float wgt = (p == pi) ? wrow[pi] : 0.0f;   // mask, don't clamp
        float dd = vv - (-310.0f + 10.0f * (float)pi);
        float g  = __expf(dd * dd * -0.005f);
        accv += wgt * g;
        accg += wgt * g * dd;
    }
    av = accv;
    ag = accg * -0.01f;
}

// ---------------------------------------------------------------------------
// kA: c0 = conv5x5(edge-pad(255*x), f0) + b0 (1->64); a0 = act(c0), g0 = act'(c0)
// grid (NT, NG), block 256; 2x2 outputs/thread; window hoisted across channels
// ---------------------------------------------------------------------------
__global__ __launch_bounds__(256) void kA(const float* __restrict__ x,
                                          const float* __restrict__ f0,
                                          const float* __restrict__ b0,
                                          const float* __restrict__ w0,
                                          float* __restrict__ a0,
                                          float* __restrict__ g0) {
    __shared__ float xs[TLH * TLH];
    __shared__ float w0s[CG][PN];

    const int tile = blockIdx.x;
    const int cg   = blockIdx.y * CG;
    const int b    = tile >> 4;
    const int t    = tile & 15;
    const int h0   = (t >> 2) * TLS;
    const int w0p  = (t & 3) * TLS;
    const int tid  = threadIdx.x;
    const int lx   = tid & 15;
    const int ly   = tid >> 4;

    for (int i = tid; i < TLH * TLH; i += 256) {
        int iy = i / TLH, ix = i - iy * TLH;
        int gy = min(max(h0 + iy - HALO, 0), IH - 1);
        int gx = min(max(w0p + ix - HALO, 0), IW - 1);
        xs[i] = x[((size_t)b * IH + gy) * IW + gx] * 255.0f;
    }
    for (int i = tid; i < CG * PN; i += 256)
        w0s[i / PN][i % PN] = w0[(size_t)cg * PN + i];
    __syncthreads();

    const int r0 = 2 * ly, c0 = 2 * lx;
    float win[6][6];
#pragma unroll
    for (int r = 0; r < 6; ++r) {
        const float2* rp = (const float2*)&xs[(r0 + r) * TLH + c0];
        float2 p0 = rp[0], p1 = rp[1], p2 = rp[2];
        win[r][0] = p0.x; win[r][1] = p0.y; win[r][2] = p1.x;
        win[r][3] = p1.y; win[r][4] = p2.x; win[r][5] = p2.y;
    }

    const int oy = h0 + r0, ox = w0p + c0;

    for (int cc = 0; cc < CG; ++cc) {
        const int c = cg + cc;
        const float bias = b0[c];
        float a00 = bias, a01 = bias, a10 = bias, a11 = bias;
#pragma unroll
        for (int u = 0; u < 5; ++u)
#pragma unroll
            for (int v = 0; v < 5; ++v) {
                const float kv = f0[(size_t)c * 25 + u * 5 + v];  // wave-uniform -> s_load
                a00 += win[u][v]     * kv;
                a01 += win[u][v + 1] * kv;
                a10 += win[u + 1][v] * kv;
                a11 += win[u + 1][v + 1] * kv;
            }
        float av0, ag0, av1, ag1, av2, ag2, av3, ag3;
        act_vg(a00, w0s[cc], av0, ag0);
        act_vg(a01, w0s[cc], av1, ag1);
        act_vg(a10, w0s[cc], av2, ag2);
        act_vg(a11, w0s[cc], av3, ag3);

        const size_t base = (((size_t)b * CH + c) * IH + oy) * IW + ox;
        *(float2*)&a0[base]      = make_float2(av0, av1);
        *(float2*)&a0[base + IW] = make_float2(av2, av3);
        *(float2*)&g0[base]      = make_float2(ag0, ag1);
        *(float2*)&g0[base + IW] = make_float2(ag2, ag3);
    }
}

// ---------------------------------------------------------------------------
// kB1: partial c1 over an 8-channel group (edge-pad conv, 64->1)
// grid (NT, NG), block 256; 2x2 outputs/thread
// ---------------------------------------------------------------------------
__global__ __launch_bounds__(256) void kB1(const float* __restrict__ a0,
                                           const float* __restrict__ f1,
                                           float* __restrict__ c1p) {
    __shared__ float as[CG][TLH * TLH];   // 41.5 KB

    const int tile = blockIdx.x;
    const int cgi  = blockIdx.y;
    const int cg   = cgi * CG;
    const int b    = tile >> 4;
    const int t    = tile & 15;
    const int h0   = (t >> 2) * TLS;
    const int w0p  = (t & 3) * TLS;
    const int tid  = threadIdx.x;
    const int lx   = tid & 15;
    const int ly   = tid >> 4;

    for (int i = tid; i < CG * TLH * TLH; i += 256) {
        int cc = i / (TLH * TLH);
        int r  = i - cc * (TLH * TLH);
        int iy = r / TLH, ix = r - iy * TLH;
        int gy = min(max(h0 + iy - HALO, 0), IH - 1);
        int gx = min(max(w0p + ix - HALO, 0), IW - 1);
        as[cc][r] = a0[(((size_t)b * CH + cg + cc) * IH + gy) * IW + gx];
    }
    __syncthreads();

    const int r0 = 2 * ly, c0 = 2 * lx;
    float a00 = 0.f, a01 = 0.f, a10 = 0.f, a11 = 0.f;

#pragma unroll 2
    for (int cc = 0; cc < CG; ++cc) {
        float win[6][6];
#pragma unroll
        for (int r = 0; r < 6; ++r) {
            const float2* rp = (const float2*)&as[cc][(r0 + r) * TLH + c0];
            float2 p0 = rp[0], p1 = rp[1], p2 = rp[2];
            win[r][0] = p0.x; win[r][1] = p0.y; win[r][2] = p1.x;
            win[r][3] = p1.y; win[r][4] = p2.x; win[r][5] = p2.y;
        }
#pragma unroll
        for (int u = 0; u < 5; ++u)
#pragma unroll
            for (int v = 0; v < 5; ++v) {
                const float kv = f1[(size_t)(cg + cc) * 25 + u * 5 + v];
                a00 += win[u][v]     * kv;
                a01 += win[u][v + 1] * kv;
                a10 += win[u + 1][v] * kv;
                a11 += win[u + 1][v + 1] * kv;
            }
    }

    const int oy = h0 + r0, ox = w0p + c0;
    const size_t base = (size_t)cgi * NPIX + ((size_t)b * IH + oy) * IW + ox;
    *(float2*)&c1p[base]      = make_float2(a00, a01);
    *(float2*)&c1p[base + IW] = make_float2(a10, a11);
}

// ---------------------------------------------------------------------------
// kB2: c1 = b1 + sum of 8 partials; a1 = act(c1, w1)
// ---------------------------------------------------------------------------
__global__ __launch_bounds__(256) void kB2(const float* __restrict__ c1p,
                                           const float* __restrict__ b1,
                                           const float* __restrict__ w1,
                                           float* __restrict__ a1) {
    __shared__ float w1s[PN];
    const int tid = threadIdx.x;
    if (tid < PN) w1s[tid] = w1[tid];
    __syncthreads();

    const int pid = blockIdx.x * 256 + tid;
    float vv = b1[0];
#pragma unroll
    for (int g = 0; g < NG; ++g) vv += c1p[(size_t)g * NPIX + pid];

    float av, ag;
    act_vg(vv, w1s, av, ag);   // ag unused
    a1[pid] = av;
}

// ---------------------------------------------------------------------------
// kC: d1[b,c,h,w] = sum_{u,v} f1[c,u,v] * a1[b,h+2-u,w+2-v] (zero pad)
//     dbuf = d1 * g0   (in place over g0)
// grid (NT, NG), block 256; window hoisted across the 8 output channels
// ---------------------------------------------------------------------------
__global__ __launch_bounds__(256) void kC(const float* __restrict__ a1,
                                          const float* __restrict__ f1,
                                          const float* __restrict__ g0,
                                          float* __restrict__ dbuf) {
    __shared__ float as1[TLH * TLH];

    const int tile = blockIdx.x;
    const int cg   = blockIdx.y * CG;
    const int b    = tile >> 4;
    const int t    = tile & 15;
    const int h0   = (t >> 2) * TLS;
    const int w0p  = (t & 3) * TLS;
    const int tid  = threadIdx.x;
    const int lx   = tid & 15;
    const int ly   = tid >> 4;

    for (int i = tid; i < TLH * TLH; i += 256) {
        int iy = i / TLH, ix = i - iy * TLH;
        int gy = h0 + iy - HALO, gx = w0p + ix - HALO;
        float v = 0.0f;
        if (gy >= 0 && gy < IH && gx >= 0 && gx < IW)
            v = a1[((size_t)b * IH + gy) * IW + gx];
        as1[i] = v;
    }
    __syncthreads();

    const int r0 = 2 * ly, c0 = 2 * lx;
    float win[6][6];
#pragma unroll
    for (int r = 0; r < 6; ++r) {
        const float2* rp = (const float2*)&as1[(r0 + r) * TLH + c0];
        float2 p0 = rp[0], p1 = rp[1], p2 = rp[2];
        win[r][0] = p0.x; win[r][1] = p0.y; win[r][2] = p1.x;
        win[r][3] = p1.y; win[r][4] = p2.x; win[r][5] = p2.y;
    }

    const int oy = h0 + r0, ox = w0p + c0;

    for (int cc = 0; cc < CG; ++cc) {
        const int c = cg + cc;
        float a00 = 0.f, a01 = 0.f, a10 = 0.f, a11 = 0.f;
#pragma unroll
        for (int u = 0; u < 5; ++u)
#pragma unroll
            for (int v = 0; v < 5; ++v) {
                const float kv = f1[(size_t)c * 25 + u * 5 + v];
                a00 += win[4 - u][4 - v]     * kv;
                a01 += win[4 - u][5 - v]     * kv;
                a10 += win[5 - u][4 - v]     * kv;
                a11 += win[5 - u][5 - v]     * kv;
            }
        const size_t base = (((size_t)b * CH + c) * IH + oy) * IW + ox;
        float2 gA = *(const float2*)&g0[base];
        float2 gB = *(const float2*)&g0[base + IW];
        *(float2*)&dbuf[base]      = make_float2(a00 * gA.x, a01 * gA.y);
        *(float2*)&dbuf[base + IW] = make_float2(a10 * gB.x, a11 * gB.y);
    }
}

// ---------------------------------------------------------------------------
// kD1: partial d3 over an 8-channel group (zero-pad full-corr, 64->1)
// grid (NT, NG), block 256
// ---------------------------------------------------------------------------
__global__ __launch_bounds__(256) void kD1(const float* __restrict__ dbuf,
                                           const float* __restrict__ f0,
                                           float* __restrict__ d3p) {
    __shared__ float ds[CG][TLH * TLH];

    const int tile = blockIdx.x;
    const int cgi  = blockIdx.y;
    const int cg   = cgi * CG;
    const int b    = tile >> 4;
    const int t    = tile & 15;
    const int h0   = (t >> 2) * TLS;
    const int w0p  = (t & 3) * TLS;
    const int tid  = threadIdx.x;
    const int lx   = tid & 15;
    const int ly   = tid >> 4;

    for (int i = tid; i < CG * TLH * TLH; i += 256) {
        int cc = i / (TLH * TLH);
        int r  = i - cc * (TLH * TLH);
        int iy = r / TLH, ix = r - iy * TLH;
        int gy = h0 + iy - HALO, gx = w0p + ix - HALO;
        float v = 0.0f;
        if (gy >= 0 && gy < IH && gx >= 0 && gx < IW)
            v = dbuf[(((size_t)b * CH + cg + cc) * IH + gy) * IW + gx];
        ds[cc][r] = v;
    }
    __syncthreads();

    const int r0 = 2 * ly, c0 = 2 * lx;
    float a00 = 0.f, a01 = 0.f, a10 = 0.f, a11 = 0.f;

#pragma unroll 2
    for (int cc = 0; cc < CG; ++cc) {
        float win[6][6];
#pragma unroll
        for (int r = 0; r < 6; ++r) {
            const float2* rp = (const float2*)&ds[cc][(r0 + r) * TLH + c0];
            float2 p0 = rp[0], p1 = rp[1], p2 = rp[2];
            win[r][0] = p0.x; win[r][1] = p0.y; win[r][2] = p1.x;
            win[r][3] = p1.y; win[r][4] = p2.x; win[r][5] = p2.y;
        }
#pragma unroll
        for (int u = 0; u < 5; ++u)
#pragma unroll
            for (int v = 0; v < 5; ++v) {
                const float kv = f0[(size_t)(cg + cc) * 25 + u * 5 + v];
                a00 += win[4 - u][4 - v] * kv;
                a01 += win[4 - u][5 - v] * kv;
                a10 += win[5 - u][4 - v] * kv;
                a11 += win[5 - u][5 - v] * kv;
            }
    }

    const int oy = h0 + r0, ox = w0p + c0;
    const size_t base = (size_t)cgi * NPIX + ((size_t)b * IH + oy) * IW + ox;
    *(float2*)&d3p[base]      = make_float2(a00, a01);
    *(float2*)&d3p[base + IW] = make_float2(a10, a11);
}

// ---------------------------------------------------------------------------
// kD2: out = x - (sum of 8 partials)/255 - exp(lam)*(x-y)
// ---------------------------------------------------------------------------
__global__ __launch_bounds__(256) void kD2(const float* __restrict__ d3p,
                                           const float* __restrict__ x,
                                           const float* __restrict__ y,
                                           const float* __restrict__ lam_param,
                                           float* __restrict__ out) {
    const int pid = blockIdx.x * 256 + threadIdx.x;
    float d3 = 0.0f;
#pragma unroll
    for (int g = 0; g < NG; ++g) d3 += d3p[(size_t)g * NPIX + pid];
    const float elam = __expf(lam_param[0]);
    const float xv = x[pid], yv = y[pid];
    out[pid] = xv - d3 * (1.0f / 255.0f) - elam * (xv - yv);
}

// ---------------------------------------------------------------------------
extern "C" void kernel_launch(void* const* d_in, const int* in_sizes, int n_in,
                              void* d_out, int out_size, void* d_ws, size_t ws_size,
                              hipStream_t stream) {
    const float* x   = (const float*)d_in[0];
    const float* y   = (const float*)d_in[1];
    // d_in[2] = lam (ignored by reference)
    const float* f0  = (const float*)d_in[3];
    const float* b0  = (const float*)d_in[4];
    const float* f1  = (const float*)d_in[5];
    const float* b1  = (const float*)d_in[6];
    const float* w0  = (const float*)d_in[7];
    const float* w1  = (const float*)d_in[8];
    const float* lam = (const float*)d_in[9];
    float* out = (float*)d_out;

    const size_t nch = (size_t)BSZ * CH * IH * IW;   // 4.19M floats
    float* a0   = (float*)d_ws;          // dead after kB1
    float* g0   = a0 + nch;              // kC writes dbuf in place
    float* a1   = g0 + nch;              // NPIX
    float* c1p  = a1 + NPIX;             // NG*NPIX partials (kB1 -> kB2)
    float* dbuf = g0;
    float* d3p  = a0;                    // reuse a0 (kD1 -> kD2)

    kA <<<dim3(NT, NG), 256, 0, stream>>>(x, f0, b0, w0, a0, g0);
    kB1<<<dim3(NT, NG), 256, 0, stream>>>(a0, f1, c1p);
    kB2<<<NPIX / 256, 256, 0, stream>>>(c1p, b1, w1, a1);
    kC <<<dim3(NT, NG), 256, 0, stream>>>(a1, f1, g0, dbuf);
    kD1<<<dim3(NT, NG), 256, 0, stream>>>(dbuf, f0, d3p);
    kD2<<<NPIX / 256, 256, 0, stream>>>(d3p, x, y, lam, out);
}

// Round 4
// 141.815 us; speedup vs baseline: 1.8293x; 1.0921x over previous
//
#include <hip/hip_runtime.h>

// Problem constants
#define BSZ 4
#define CH 64
#define IH 128
#define IW 128
#define PN 63          // number of gaussians
#define TLS 32         // 32x32 outputs per block
#define TLH 36         // extended region for 5x5 halo
#define XSD 40         // x staging (halo of halo)
#define NT 64          // 4 images * 4*4 tiles
#define CG 8           // channels per group
#define NG 8           // channel groups
#define NPIX (BSZ*IH*IW)   // 65536

// ---------------------------------------------------------------------------
// Fast gaussian-mixture activation:
//   exp(-(d0-10j)^2/200) = G0 * T^j * C_j,  G0=exp(-d0^2/200), T=exp(d0/10),
//   C_j = exp(-j^2/2). 3 transcendentals replace 9 exps. Window j=-4..4
//   (taps beyond |d|>=45 are < 4.1e-5 relative -> negligible).
// ---------------------------------------------------------------------------
__device__ __forceinline__ float wsel(const float* __restrict__ wrow, int pc, int j) {
    int p  = pc + j;
    int pi = min(max(p, 0), PN - 1);
    return (p == pi) ? wrow[pi] : 0.0f;   // mask out-of-range taps
}

__device__ __forceinline__ void act_vg(float vv, const float* __restrict__ wrow,
                                       float& av, float& ag) {
    float pcf = floorf(__fmaf_rn(vv, 0.1f, 31.5f));
    pcf = fminf(fmaxf(pcf, 0.0f), 62.0f);
    const int pc = (int)pcf;
    float d0 = vv - __fmaf_rn(pcf, 10.0f, -310.0f);
    d0 = fminf(fmaxf(d0, -150.0f), 150.0f);   // G0 underflows anyway; keeps T^4 finite
    const float G0 = __expf(d0 * d0 * -0.005f);
    const float T  = __expf(d0 * 0.1f);
    const float Ti = __expf(d0 * -0.1f);
    const float C1 = 0.60653066f, C2 = 0.13533528f, C3 = 0.011108997f, C4 = 4.0867714e-4f;
    float accv, accg;
    {
        float t = wsel(wrow, pc, 0) * G0;
        accv = t; accg = t * d0;
    }
    float Tp = T, Tm = Ti;
    {
        float gc = G0 * C1;
        float tp = wsel(wrow, pc,  1) * (gc * Tp);
        float tm = wsel(wrow, pc, -1) * (gc * Tm);
        accv += tp + tm;
        accg = __fmaf_rn(tp, d0 - 10.0f, accg);
        accg = __fmaf_rn(tm, d0 + 10.0f, accg);
    }
    Tp *= T; Tm *= Ti;
    {
        float gc = G0 * C2;
        float tp = wsel(wrow, pc,  2) * (gc * Tp);
        float tm = wsel(wrow, pc, -2) * (gc * Tm);
        accv += tp + tm;
        accg = __fmaf_rn(tp, d0 - 20.0f, accg);
        accg = __fmaf_rn(tm, d0 + 20.0f, accg);
    }
    Tp *= T; Tm *= Ti;
    {
        float gc = G0 * C3;
        float tp = wsel(wrow, pc,  3) * (gc * Tp);
        float tm = wsel(wrow, pc, -3) * (gc * Tm);
        accv += tp + tm;
        accg = __fmaf_rn(tp, d0 - 30.0f, accg);
        accg = __fmaf_rn(tm, d0 + 30.0f, accg);
    }
    Tp *= T; Tm *= Ti;
    {
        float gc = G0 * C4;
        float tp = wsel(wrow, pc,  4) * (gc * Tp);
        float tm = wsel(wrow, pc, -4) * (gc * Tm);
        accv += tp + tm;
        accg = __fmaf_rn(tp, d0 - 40.0f, accg);
        accg = __fmaf_rn(tm, d0 + 40.0f, accg);
    }
    av = accv;
    ag = accg * -0.01f;
}

__device__ __forceinline__ float act_v(float vv, const float* __restrict__ wrow) {
    float pcf = floorf(__fmaf_rn(vv, 0.1f, 31.5f));
    pcf = fminf(fmaxf(pcf, 0.0f), 62.0f);
    const int pc = (int)pcf;
    float d0 = vv - __fmaf_rn(pcf, 10.0f, -310.0f);
    d0 = fminf(fmaxf(d0, -150.0f), 150.0f);
    const float G0 = __expf(d0 * d0 * -0.005f);
    const float T  = __expf(d0 * 0.1f);
    const float Ti = __expf(d0 * -0.1f);
    const float C1 = 0.60653066f, C2 = 0.13533528f, C3 = 0.011108997f, C4 = 4.0867714e-4f;
    float accv = wsel(wrow, pc, 0) * G0;
    float Tp = T, Tm = Ti;
    accv += G0 * C1 * (wsel(wrow, pc, 1) * Tp + wsel(wrow, pc, -1) * Tm);
    Tp *= T; Tm *= Ti;
    accv += G0 * C2 * (wsel(wrow, pc, 2) * Tp + wsel(wrow, pc, -2) * Tm);
    Tp *= T; Tm *= Ti;
    accv += G0 * C3 * (wsel(wrow, pc, 3) * Tp + wsel(wrow, pc, -3) * Tm);
    Tp *= T; Tm *= Ti;
    accv += G0 * C4 * (wsel(wrow, pc, 4) * Tp + wsel(wrow, pc, -4) * Tm);
    return accv;
}

// ---------------------------------------------------------------------------
// kAB: fused kA + kB1.  Per block (tile, channel-group of 8):
//   - stage x (40x40, edge-clamped, *255) in LDS
//   - compute a0 = act(conv5(x)+b0) on the EXTENDED 36x36 region (evaluation
//     centers edge-clamped == rep_pad(a0) semantics); a0 stays in LDS.
//     g0 = act'(...) written to global for interior 32x32 only.
//   - accumulate partial c1 = sum_cc f1_cc (*) a0_cc on 32x32 (2x2/thread).
// a0 never touches HBM.
// ---------------------------------------------------------------------------
__global__ __launch_bounds__(256) void kAB(const float* __restrict__ x,
                                           const float* __restrict__ f0,
                                           const float* __restrict__ b0,
                                           const float* __restrict__ w0,
                                           const float* __restrict__ f1,
                                           float* __restrict__ c1p,
                                           float* __restrict__ g0out) {
    __shared__ float xs[XSD * XSD];          // 6.4 KB
    __shared__ float a0s[CG][TLH * TLH];     // 41.5 KB
    __shared__ float w0s[CG][PN];            // 2.0 KB

    const int tile = blockIdx.x;
    const int cgi  = blockIdx.y;
    const int cg   = cgi * CG;
    const int b    = tile >> 4;
    const int t    = tile & 15;
    const int h0   = (t >> 2) * TLS;
    const int w0p  = (t & 3) * TLS;
    const int tid  = threadIdx.x;

    for (int i = tid; i < XSD * XSD; i += 256) {
        int iy = i / XSD, ix = i - iy * XSD;
        int gy = min(max(h0 + iy - 4, 0), IH - 1);
        int gx = min(max(w0p + ix - 4, 0), IW - 1);
        xs[i] = x[((size_t)b * IH + gy) * IW + gx] * 255.0f;
    }
    for (int i = tid; i < CG * PN; i += 256)
        w0s[i / PN][i % PN] = w0[(size_t)cg * PN + i];
    __syncthreads();

    // a0 / g0 on extended region, px-major (window hoisted across 8 channels)
    for (int p = tid; p < TLH * TLH; p += 256) {
        const int py = p / TLH, px = p - py * TLH;
        const int gy = h0 + py - 2, gx = w0p + px - 2;
        const int gyc = min(max(gy, 0), IH - 1);
        const int gxc = min(max(gx, 0), IW - 1);
        const bool interior = (gy == gyc) && (gx == gxc);
        const int cy = gyc - h0 + 4, cx = gxc - w0p + 4;

        float win[25];
#pragma unroll
        for (int u = 0; u < 5; ++u)
#pragma unroll
            for (int v = 0; v < 5; ++v)
                win[u * 5 + v] = xs[(cy - 2 + u) * XSD + cx - 2 + v];

#pragma unroll
        for (int cc = 0; cc < CG; ++cc) {
            const int c = cg + cc;
            float acc = b0[c];
#pragma unroll
            for (int k = 0; k < 25; ++k)
                acc = __fmaf_rn(win[k], f0[(size_t)c * 25 + k], acc);
            float av, ag;
            act_vg(acc, w0s[cc], av, ag);
            a0s[cc][p] = av;
            if (interior)
                g0out[(((size_t)b * CH + c) * IH + gy) * IW + gx] = ag;
        }
    }
    __syncthreads();

    // partial c1 (2x2 outputs per thread)
    const int lx = tid & 15, ly = tid >> 4;
    const int r0 = 2 * ly, c0 = 2 * lx;
    float a00 = 0.f, a01 = 0.f, a10 = 0.f, a11 = 0.f;

#pragma unroll 2
    for (int cc = 0; cc < CG; ++cc) {
        float win[6][6];
#pragma unroll
        for (int r = 0; r < 6; ++r) {
            const float2* rp = (const float2*)&a0s[cc][(r0 + r) * TLH + c0];
            float2 p0 = rp[0], p1 = rp[1], p2 = rp[2];
            win[r][0] = p0.x; win[r][1] = p0.y; win[r][2] = p1.x;
            win[r][3] = p1.y; win[r][4] = p2.x; win[r][5] = p2.y;
        }
#pragma unroll
        for (int u = 0; u < 5; ++u)
#pragma unroll
            for (int v = 0; v < 5; ++v) {
                const float kv = f1[(size_t)(cg + cc) * 25 + u * 5 + v];
                a00 = __fmaf_rn(win[u][v],         kv, a00);
                a01 = __fmaf_rn(win[u][v + 1],     kv, a01);
                a10 = __fmaf_rn(win[u + 1][v],     kv, a10);
                a11 = __fmaf_rn(win[u + 1][v + 1], kv, a11);
            }
    }

    const int oy = h0 + r0, ox = w0p + c0;
    const size_t base = (size_t)cgi * NPIX + ((size_t)b * IH + oy) * IW + ox;
    *(float2*)&c1p[base]      = make_float2(a00, a01);
    *(float2*)&c1p[base + IW] = make_float2(a10, a11);
}

// ---------------------------------------------------------------------------
// kCD: fused kB2 + kC + kD1.  Per block (tile, channel-group of 8):
//   - recompute a1 = act(b1 + sum of 8 c1p partials) on 40x40 (zero outside
//     image: conv_transpose zero-pads) in LDS
//   - dbuf_cc = conv_t5(a1) * g0 on 36x36 into LDS (window hoisted across cc)
//   - accumulate partial d3 = sum_cc f0_cc full-corr dbuf_cc on 32x32
// dbuf never touches HBM.
// ---------------------------------------------------------------------------
__global__ __launch_bounds__(256) void kCD(const float* __restrict__ c1p,
                                           const float* __restrict__ b1,
                                           const float* __restrict__ w1,
                                           const float* __restrict__ f1,
                                           const float* __restrict__ f0,
                                           const float* __restrict__ g0,
                                           float* __restrict__ d3p) {
    __shared__ float a1s[XSD * XSD];         // 6.4 KB
    __shared__ float dbs[CG][TLH * TLH];     // 41.5 KB
    __shared__ float w1s[PN];

    const int tile = blockIdx.x;
    const int cgi  = blockIdx.y;
    const int cg   = cgi * CG;
    const int b    = tile >> 4;
    const int t    = tile & 15;
    const int h0   = (t >> 2) * TLS;
    const int w0p  = (t & 3) * TLS;
    const int tid  = threadIdx.x;

    if (tid < PN) w1s[tid] = w1[tid];
    __syncthreads();

    const float b1v = b1[0];

    // a1 on 40x40 (zero outside image)
    for (int p = tid; p < XSD * XSD; p += 256) {
        int iy = p / XSD, ix = p - iy * XSD;
        int gy = h0 + iy - 4, gx = w0p + ix - 4;
        float v = 0.0f;
        if ((unsigned)gy < IH && (unsigned)gx < IW) {
            const size_t pix = ((size_t)b * IH + gy) * IW + gx;
            float s = b1v;
#pragma unroll
            for (int g = 0; g < NG; ++g) s += c1p[(size_t)g * NPIX + pix];
            v = act_v(s, w1s);
        }
        a1s[p] = v;
    }
    __syncthreads();

    // dbuf planes on 36x36 (zero outside image)
    for (int p = tid; p < TLH * TLH; p += 256) {
        const int py = p / TLH, px = p - py * TLH;
        const int gy = h0 + py - 2, gx = w0p + px - 2;
        const bool inb = ((unsigned)gy < IH) && ((unsigned)gx < IW);

        float win[25];
#pragma unroll
        for (int u = 0; u < 5; ++u)
#pragma unroll
            for (int v = 0; v < 5; ++v)
                win[u * 5 + v] = a1s[(py + 4 - u) * XSD + (px + 4 - v)];

#pragma unroll
        for (int cc = 0; cc < CG; ++cc) {
            float out = 0.0f;
            if (inb) {
                const int c = cg + cc;
                float d1 = 0.0f;
#pragma unroll
                for (int k = 0; k < 25; ++k)
                    d1 = __fmaf_rn(win[k], f1[(size_t)c * 25 + k], d1);
                out = d1 * g0[(((size_t)b * CH + c) * IH + gy) * IW + gx];
            }
            dbs[cc][p] = out;
        }
    }
    __syncthreads();

    // partial d3 (2x2 outputs per thread), full-correlation with f0
    const int lx = tid & 15, ly = tid >> 4;
    const int r0 = 2 * ly, c0 = 2 * lx;
    float a00 = 0.f, a01 = 0.f, a10 = 0.f, a11 = 0.f;

#pragma unroll 2
    for (int cc = 0; cc < CG; ++cc) {
        float win[6][6];
#pragma unroll
        for (int r = 0; r < 6; ++r) {
            const float2* rp = (const float2*)&dbs[cc][(r0 + r) * TLH + c0];
            float2 p0 = rp[0], p1 = rp[1], p2 = rp[2];
            win[r][0] = p0.x; win[r][1] = p0.y; win[r][2] = p1.x;
            win[r][3] = p1.y; win[r][4] = p2.x; win[r][5] = p2.y;
        }
#pragma unroll
        for (int u = 0; u < 5; ++u)
#pragma unroll
            for (int v = 0; v < 5; ++v) {
                const float kv = f0[(size_t)(cg + cc) * 25 + u * 5 + v];
                a00 = __fmaf_rn(win[4 - u][4 - v], kv, a00);
                a01 = __fmaf_rn(win[4 - u][5 - v], kv, a01);
                a10 = __fmaf_rn(win[5 - u][4 - v], kv, a10);
                a11 = __fmaf_rn(win[5 - u][5 - v], kv, a11);
            }
    }

    const int oy = h0 + r0, ox = w0p + c0;
    const size_t base = (size_t)cgi * NPIX + ((size_t)b * IH + oy) * IW + ox;
    *(float2*)&d3p[base]      = make_float2(a00, a01);
    *(float2*)&d3p[base + IW] = make_float2(a10, a11);
}

// ---------------------------------------------------------------------------
// kE: out = x - (sum of 8 d3 partials)/255 - exp(lam)*(x-y)
// ---------------------------------------------------------------------------
__global__ __launch_bounds__(256) void kE(const float* __restrict__ d3p,
                                          const float* __restrict__ x,
                                          const float* __restrict__ y,
                                          const float* __restrict__ lam_param,
                                          float* __restrict__ out) {
    const int pid = blockIdx.x * 256 + threadIdx.x;
    float d3 = 0.0f;
#pragma unroll
    for (int g = 0; g < NG; ++g) d3 += d3p[(size_t)g * NPIX + pid];
    const float elam = __expf(lam_param[0]);
    const float xv = x[pid], yv = y[pid];
    out[pid] = xv - d3 * (1.0f / 255.0f) - elam * (xv - yv);
}

// ---------------------------------------------------------------------------
extern "C" void kernel_launch(void* const* d_in, const int* in_sizes, int n_in,
                              void* d_out, int out_size, void* d_ws, size_t ws_size,
                              hipStream_t stream) {
    const float* x   = (const float*)d_in[0];
    const float* y   = (const float*)d_in[1];
    // d_in[2] = lam (ignored by reference)
    const float* f0  = (const float*)d_in[3];
    const float* b0  = (const float*)d_in[4];
    const float* f1  = (const float*)d_in[5];
    const float* b1  = (const float*)d_in[6];
    const float* w0  = (const float*)d_in[7];
    const float* w1  = (const float*)d_in[8];
    const float* lam = (const float*)d_in[9];
    float* out = (float*)d_out;

    const size_t nch = (size_t)BSZ * CH * IH * IW;   // 4.19M floats
    float* g0  = (float*)d_ws;           // 16.8 MB
    float* c1p = g0 + nch;               // NG * NPIX (2 MB)
    float* d3p = c1p + (size_t)NG * NPIX;// NG * NPIX (2 MB)

    kAB<<<dim3(NT, NG), 256, 0, stream>>>(x, f0, b0, w0, f1, c1p, g0);
    kCD<<<dim3(NT, NG), 256, 0, stream>>>(c1p, b1, w1, f1, f0, g0, d3p);
    kE <<<NPIX / 256, 256, 0, stream>>>(d3p, x, y, lam, out);
}

// Round 5
// 122.044 us; speedup vs baseline: 2.1257x; 1.1620x over previous
//
#include <hip/hip_runtime.h>

// Problem constants
#define BSZ 4
#define CH 64
#define IH 128
#define IW 128
#define PN 63          // number of gaussians
#define PNP 72         // padded weight row (4 zeros each side, +1 align)
#define TLS 32         // 32x32 outputs per block
#define TLH 36         // extended region for 5x5 halo
#define XSD 40         // staging with halo-of-halo
#define NT 64          // 4 images * 4*4 tiles
#define CG 4           // channels per group
#define NG 16          // channel groups
#define NPIX (BSZ*IH*IW)   // 65536

// ---------------------------------------------------------------------------
// Fast gaussian-mixture activation, radius-3 window (7 taps):
//   exp(-(d0-10j)^2/200) = G0 * T^j * C_j,  G0=exp(-d0^2/200), T=exp(d0/10),
//   C_j=exp(-j^2/2).  3 transcendentals total.  Weight row wp[] is LDS,
//   zero-padded by 4 on each side so no tap masking is needed.
// ---------------------------------------------------------------------------
__device__ __forceinline__ void act_vg(float vv, const float* __restrict__ wp,
                                       float& av, float& ag) {
    float pcf = floorf(__fmaf_rn(vv, 0.1f, 31.5f));
    pcf = fminf(fmaxf(pcf, 0.0f), 62.0f);
    const int pc4 = (int)pcf + 4;
    float d0 = vv - __fmaf_rn(pcf, 10.0f, -310.0f);
    d0 = fminf(fmaxf(d0, -150.0f), 150.0f);   // keeps T^3 finite; G0 ~ 0 there anyway
    const float G0 = __expf(d0 * d0 * -0.005f);
    const float T  = __expf(d0 * 0.1f);
    const float Ti = __expf(d0 * -0.1f);
    float t0 = wp[pc4] * G0;
    float accv = t0, accg = t0 * d0;
    float Tp = T, Tm = Ti;
    float gc = G0 * 0.60653066f;
    float tp = wp[pc4 + 1] * (gc * Tp), tm = wp[pc4 - 1] * (gc * Tm);
    accv += tp + tm;
    accg = __fmaf_rn(tp, d0 - 10.0f, __fmaf_rn(tm, d0 + 10.0f, accg));
    Tp *= T; Tm *= Ti;
    gc = G0 * 0.13533528f;
    tp = wp[pc4 + 2] * (gc * Tp); tm = wp[pc4 - 2] * (gc * Tm);
    accv += tp + tm;
    accg = __fmaf_rn(tp, d0 - 20.0f, __fmaf_rn(tm, d0 + 20.0f, accg));
    Tp *= T; Tm *= Ti;
    gc = G0 * 0.011108997f;
    tp = wp[pc4 + 3] * (gc * Tp); tm = wp[pc4 - 3] * (gc * Tm);
    accv += tp + tm;
    accg = __fmaf_rn(tp, d0 - 30.0f, __fmaf_rn(tm, d0 + 30.0f, accg));
    av = accv;
    ag = accg * -0.01f;
}

__device__ __forceinline__ float act_v(float vv, const float* __restrict__ wp) {
    float pcf = floorf(__fmaf_rn(vv, 0.1f, 31.5f));
    pcf = fminf(fmaxf(pcf, 0.0f), 62.0f);
    const int pc4 = (int)pcf + 4;
    float d0 = vv - __fmaf_rn(pcf, 10.0f, -310.0f);
    d0 = fminf(fmaxf(d0, -150.0f), 150.0f);
    const float G0 = __expf(d0 * d0 * -0.005f);
    const float T  = __expf(d0 * 0.1f);
    const float Ti = __expf(d0 * -0.1f);
    float accv = wp[pc4] * G0;
    float Tp = T, Tm = Ti;
    accv += G0 * 0.60653066f  * (wp[pc4 + 1] * Tp + wp[pc4 - 1] * Tm);
    Tp *= T; Tm *= Ti;
    accv += G0 * 0.13533528f  * (wp[pc4 + 2] * Tp + wp[pc4 - 2] * Tm);
    Tp *= T; Tm *= Ti;
    accv += G0 * 0.011108997f * (wp[pc4 + 3] * Tp + wp[pc4 - 3] * Tm);
    return accv;
}

// ---------------------------------------------------------------------------
// kAB: fused conv0 + act + partial conv1.  Per block (tile, 4-channel group):
//   - stage x (40x40, edge-clamped, *255) in LDS
//   - a0 = act(conv5(x)+b0) on extended 36x36 (centers edge-clamped ==
//     rep_pad semantics); a0 stays in LDS; g0 = act' stored for interior.
//   - partial c1 = sum_cc f1_cc (*) a0_cc on 32x32, 2x2/thread.
// ---------------------------------------------------------------------------
__global__ __launch_bounds__(256) void kAB(const float* __restrict__ x,
                                           const float* __restrict__ f0,
                                           const float* __restrict__ b0,
                                           const float* __restrict__ w0,
                                           const float* __restrict__ f1,
                                           float* __restrict__ c1p,
                                           float* __restrict__ g0out) {
    __shared__ float xs[XSD * XSD];          // 6.4 KB
    __shared__ float a0s[CG][TLH * TLH];     // 20.7 KB
    __shared__ float w0ps[CG][PNP];          // 1.2 KB

    const int tile = blockIdx.x;
    const int cgi  = blockIdx.y;
    const int cg   = cgi * CG;
    const int b    = tile >> 4;
    const int t    = tile & 15;
    const int h0   = (t >> 2) * TLS;
    const int w0p  = (t & 3) * TLS;
    const int tid  = threadIdx.x;

    for (int i = tid; i < XSD * XSD; i += 256) {
        int iy = i / XSD, ix = i - iy * XSD;
        int gy = min(max(h0 + iy - 4, 0), IH - 1);
        int gx = min(max(w0p + ix - 4, 0), IW - 1);
        xs[i] = x[((size_t)b * IH + gy) * IW + gx] * 255.0f;
    }
    for (int i = tid; i < CG * PNP; i += 256) {
        int cc = i / PNP, k = i - cc * PNP;
        float v = 0.0f;
        if (k >= 4 && k < 4 + PN) v = w0[(size_t)(cg + cc) * PN + (k - 4)];
        w0ps[cc][k] = v;
    }
    __syncthreads();

    // a0 / g0 on extended region (window hoisted across the 4 channels)
    for (int p = tid; p < TLH * TLH; p += 256) {
        const int py = p / TLH, px = p - py * TLH;
        const int gy = h0 + py - 2, gx = w0p + px - 2;
        const int gyc = min(max(gy, 0), IH - 1);
        const int gxc = min(max(gx, 0), IW - 1);
        const bool interior = (gy == gyc) && (gx == gxc);
        const int cy = gyc - h0 + 4, cx = gxc - w0p + 4;

        float win[25];
#pragma unroll
        for (int u = 0; u < 5; ++u)
#pragma unroll
            for (int v = 0; v < 5; ++v)
                win[u * 5 + v] = xs[(cy - 2 + u) * XSD + cx - 2 + v];

#pragma unroll
        for (int cc = 0; cc < CG; ++cc) {
            const int c = cg + cc;
            float acc = b0[c];
#pragma unroll
            for (int k = 0; k < 25; ++k)
                acc = __fmaf_rn(win[k], f0[(size_t)c * 25 + k], acc);
            float av, ag;
            act_vg(acc, w0ps[cc], av, ag);
            a0s[cc][p] = av;
            if (interior)
                g0out[(((size_t)b * CH + c) * IH + gy) * IW + gx] = ag;
        }
    }
    __syncthreads();

    // partial c1 (2x2 outputs per thread)
    const int lx = tid & 15, ly = tid >> 4;
    const int r0 = 2 * ly, c0 = 2 * lx;
    float a00 = 0.f, a01 = 0.f, a10 = 0.f, a11 = 0.f;

#pragma unroll
    for (int cc = 0; cc < CG; ++cc) {
        float win[6][6];
#pragma unroll
        for (int r = 0; r < 6; ++r) {
            const float2* rp = (const float2*)&a0s[cc][(r0 + r) * TLH + c0];
            float2 p0 = rp[0], p1 = rp[1], p2 = rp[2];
            win[r][0] = p0.x; win[r][1] = p0.y; win[r][2] = p1.x;
            win[r][3] = p1.y; win[r][4] = p2.x; win[r][5] = p2.y;
        }
#pragma unroll
        for (int u = 0; u < 5; ++u)
#pragma unroll
            for (int v = 0; v < 5; ++v) {
                const float kv = f1[(size_t)(cg + cc) * 25 + u * 5 + v];
                a00 = __fmaf_rn(win[u][v],         kv, a00);
                a01 = __fmaf_rn(win[u][v + 1],     kv, a01);
                a10 = __fmaf_rn(win[u + 1][v],     kv, a10);
                a11 = __fmaf_rn(win[u + 1][v + 1], kv, a11);
            }
    }

    const int oy = h0 + r0, ox = w0p + c0;
    const size_t base = (size_t)cgi * NPIX + ((size_t)b * IH + oy) * IW + ox;
    *(float2*)&c1p[base]      = make_float2(a00, a01);
    *(float2*)&c1p[base + IW] = make_float2(a10, a11);
}

// ---------------------------------------------------------------------------
// kB2: a1 = act(b1 + sum of 16 c1p partials, w1)
// ---------------------------------------------------------------------------
__global__ __launch_bounds__(256) void kB2(const float* __restrict__ c1p,
                                           const float* __restrict__ b1,
                                           const float* __restrict__ w1,
                                           float* __restrict__ a1) {
    __shared__ float w1p[PNP];
    const int tid = threadIdx.x;
    if (tid < PNP) {
        float v = 0.0f;
        if (tid >= 4 && tid < 4 + PN) v = w1[tid - 4];
        w1p[tid] = v;
    }
    __syncthreads();

    const int pid = blockIdx.x * 256 + tid;
    float vv = b1[0];
#pragma unroll
    for (int g = 0; g < NG; ++g) vv += c1p[(size_t)g * NPIX + pid];
    a1[pid] = act_v(vv, w1p);
}

// ---------------------------------------------------------------------------
// kCD: per block (tile, 4-channel group):
//   - stage a1 (40x40, zero outside image) in LDS
//   - dbuf_cc = conv_t5(a1) * g0 on 36x36 into LDS (window hoisted over cc)
//   - partial d3 = sum_cc f0_cc full-corr dbuf_cc on 32x32, 2x2/thread.
// ---------------------------------------------------------------------------
__global__ __launch_bounds__(256) void kCD(const float* __restrict__ a1,
                                           const float* __restrict__ f1,
                                           const float* __restrict__ f0,
                                           const float* __restrict__ g0,
                                           float* __restrict__ d3p) {
    __shared__ float a1s[XSD * XSD];         // 6.4 KB
    __shared__ float dbs[CG][TLH * TLH];     // 20.7 KB

    const int tile = blockIdx.x;
    const int cgi  = blockIdx.y;
    const int cg   = cgi * CG;
    const int b    = tile >> 4;
    const int t    = tile & 15;
    const int h0   = (t >> 2) * TLS;
    const int w0p  = (t & 3) * TLS;
    const int tid  = threadIdx.x;

    for (int p = tid; p < XSD * XSD; p += 256) {
        int iy = p / XSD, ix = p - iy * XSD;
        int gy = h0 + iy - 4, gx = w0p + ix - 4;
        float v = 0.0f;
        if ((unsigned)gy < IH && (unsigned)gx < IW)
            v = a1[((size_t)b * IH + gy) * IW + gx];
        a1s[p] = v;
    }
    __syncthreads();

    for (int p = tid; p < TLH * TLH; p += 256) {
        const int py = p / TLH, px = p - py * TLH;
        const int gy = h0 + py - 2, gx = w0p + px - 2;
        const bool inb = ((unsigned)gy < IH) && ((unsigned)gx < IW);

        float win[25];
#pragma unroll
        for (int u = 0; u < 5; ++u)
#pragma unroll
            for (int v = 0; v < 5; ++v)
                win[u * 5 + v] = a1s[(py + 4 - u) * XSD + (px + 4 - v)];

#pragma unroll
        for (int cc = 0; cc < CG; ++cc) {
            float out = 0.0f;
            if (inb) {
                const int c = cg + cc;
                float d1 = 0.0f;
#pragma unroll
                for (int k = 0; k < 25; ++k)
                    d1 = __fmaf_rn(win[k], f1[(size_t)c * 25 + k], d1);
                out = d1 * g0[(((size_t)b * CH + c) * IH + gy) * IW + gx];
            }
            dbs[cc][p] = out;
        }
    }
    __syncthreads();

    const int lx = tid & 15, ly = tid >> 4;
    const int r0 = 2 * ly, c0 = 2 * lx;
    float a00 = 0.f, a01 = 0.f, a10 = 0.f, a11 = 0.f;

#pragma unroll
    for (int cc = 0; cc < CG; ++cc) {
        float win[6][6];
#pragma unroll
        for (int r = 0; r < 6; ++r) {
            const float2* rp = (const float2*)&dbs[cc][(r0 + r) * TLH + c0];
            float2 p0 = rp[0], p1 = rp[1], p2 = rp[2];
            win[r][0] = p0.x; win[r][1] = p0.y; win[r][2] = p1.x;
            win[r][3] = p1.y; win[r][4] = p2.x; win[r][5] = p2.y;
        }
#pragma unroll
        for (int u = 0; u < 5; ++u)
#pragma unroll
            for (int v = 0; v < 5; ++v) {
                const float kv = f0[(size_t)(cg + cc) * 25 + u * 5 + v];
                a00 = __fmaf_rn(win[4 - u][4 - v], kv, a00);
                a01 = __fmaf_rn(win[4 - u][5 - v], kv, a01);
                a10 = __fmaf_rn(win[5 - u][4 - v], kv, a10);
                a11 = __fmaf_rn(win[5 - u][5 - v], kv, a11);
            }
    }

    const int oy = h0 + r0, ox = w0p + c0;
    const size_t base = (size_t)cgi * NPIX + ((size_t)b * IH + oy) * IW + ox;
    *(float2*)&d3p[base]      = make_float2(a00, a01);
    *(float2*)&d3p[base + IW] = make_float2(a10, a11);
}

// ---------------------------------------------------------------------------
// kE: out = x - (sum of 16 d3 partials)/255 - exp(lam)*(x-y)
// ---------------------------------------------------------------------------
__global__ __launch_bounds__(256) void kE(const float* __restrict__ d3p,
                                          const float* __restrict__ x,
                                          const float* __restrict__ y,
                                          const float* __restrict__ lam_param,
                                          float* __restrict__ out) {
    const int pid = blockIdx.x * 256 + threadIdx.x;
    float d3 = 0.0f;
#pragma unroll
    for (int g = 0; g < NG; ++g) d3 += d3p[(size_t)g * NPIX + pid];
    const float elam = __expf(lam_param[0]);
    const float xv = x[pid], yv = y[pid];
    out[pid] = xv - d3 * (1.0f / 255.0f) - elam * (xv - yv);
}

// ---------------------------------------------------------------------------
extern "C" void kernel_launch(void* const* d_in, const int* in_sizes, int n_in,
                              void* d_out, int out_size, void* d_ws, size_t ws_size,
                              hipStream_t stream) {
    const float* x   = (const float*)d_in[0];
    const float* y   = (const float*)d_in[1];
    // d_in[2] = lam (ignored by reference)
    const float* f0  = (const float*)d_in[3];
    const float* b0  = (const float*)d_in[4];
    const float* f1  = (const float*)d_in[5];
    const float* b1  = (const float*)d_in[6];
    const float* w0  = (const float*)d_in[7];
    const float* w1  = (const float*)d_in[8];
    const float* lam = (const float*)d_in[9];
    float* out = (float*)d_out;

    const size_t nch = (size_t)BSZ * CH * IH * IW;   // 4.19M floats
    float* g0  = (float*)d_ws;             // 16.8 MB
    float* a1  = g0 + nch;                 // 0.26 MB
    float* c1p = a1 + NPIX;                // NG * NPIX (4.2 MB)
    float* d3p = c1p + (size_t)NG * NPIX;  // NG * NPIX (4.2 MB)

    kAB<<<dim3(NT, NG), 256, 0, stream>>>(x, f0, b0, w0, f1, c1p, g0);
    kB2<<<NPIX / 256, 256, 0, stream>>>(c1p, b1, w1, a1);
    kCD<<<dim3(NT, NG), 256, 0, stream>>>(a1, f1, f0, g0, d3p);
    kE <<<NPIX / 256, 256, 0, stream>>>(d3p, x, y, lam, out);
}

// Round 6
// 121.959 us; speedup vs baseline: 2.1271x; 1.0007x over previous
//
#include <hip/hip_runtime.h>
#include <hip/hip_bf16.h>

// Problem constants
#define BSZ 4
#define CH 64
#define IH 128
#define IW 128
#define PN 63          // number of gaussians
#define PNP 72         // padded weight row (4 zeros each side, +1 align)
#define TLS 32         // 32x32 outputs per block
#define TLH 36         // extended region for 5x5 halo
#define XSD 40         // staging with halo-of-halo
#define NT 64          // 4 images * 4*4 tiles
#define CG 2           // channels per group
#define NG 32          // channel groups
#define NPIX (BSZ*IH*IW)   // 65536

// ---------------------------------------------------------------------------
// Fast gaussian-mixture activation, radius-3 window (7 taps):
//   exp(-(d0-10j)^2/200) = G0 * T^j * C_j,  G0=exp(-d0^2/200), T=exp(d0/10),
//   C_j=exp(-j^2/2).  3 transcendentals total.  Weight row wp[] is LDS,
//   zero-padded by 4 on each side so no tap masking is needed.
// ---------------------------------------------------------------------------
__device__ __forceinline__ void act_vg(float vv, const float* __restrict__ wp,
                                       float& av, float& ag) {
    float pcf = floorf(__fmaf_rn(vv, 0.1f, 31.5f));
    pcf = fminf(fmaxf(pcf, 0.0f), 62.0f);
    const int pc4 = (int)pcf + 4;
    float d0 = vv - __fmaf_rn(pcf, 10.0f, -310.0f);
    d0 = fminf(fmaxf(d0, -150.0f), 150.0f);   // keeps T^3 finite; G0 ~ 0 there anyway
    const float G0 = __expf(d0 * d0 * -0.005f);
    const float T  = __expf(d0 * 0.1f);
    const float Ti = __expf(d0 * -0.1f);
    float t0 = wp[pc4] * G0;
    float accv = t0, accg = t0 * d0;
    float Tp = T, Tm = Ti;
    float gc = G0 * 0.60653066f;
    float tp = wp[pc4 + 1] * (gc * Tp), tm = wp[pc4 - 1] * (gc * Tm);
    accv += tp + tm;
    accg = __fmaf_rn(tp, d0 - 10.0f, __fmaf_rn(tm, d0 + 10.0f, accg));
    Tp *= T; Tm *= Ti;
    gc = G0 * 0.13533528f;
    tp = wp[pc4 + 2] * (gc * Tp); tm = wp[pc4 - 2] * (gc * Tm);
    accv += tp + tm;
    accg = __fmaf_rn(tp, d0 - 20.0f, __fmaf_rn(tm, d0 + 20.0f, accg));
    Tp *= T; Tm *= Ti;
    gc = G0 * 0.011108997f;
    tp = wp[pc4 + 3] * (gc * Tp); tm = wp[pc4 - 3] * (gc * Tm);
    accv += tp + tm;
    accg = __fmaf_rn(tp, d0 - 30.0f, __fmaf_rn(tm, d0 + 30.0f, accg));
    av = accv;
    ag = accg * -0.01f;
}

__device__ __forceinline__ float act_v(float vv, const float* __restrict__ wp) {
    float pcf = floorf(__fmaf_rn(vv, 0.1f, 31.5f));
    pcf = fminf(fmaxf(pcf, 0.0f), 62.0f);
    const int pc4 = (int)pcf + 4;
    float d0 = vv - __fmaf_rn(pcf, 10.0f, -310.0f);
    d0 = fminf(fmaxf(d0, -150.0f), 150.0f);
    const float G0 = __expf(d0 * d0 * -0.005f);
    const float T  = __expf(d0 * 0.1f);
    const float Ti = __expf(d0 * -0.1f);
    float accv = wp[pc4] * G0;
    float Tp = T, Tm = Ti;
    accv += G0 * 0.60653066f  * (wp[pc4 + 1] * Tp + wp[pc4 - 1] * Tm);
    Tp *= T; Tm *= Ti;
    accv += G0 * 0.13533528f  * (wp[pc4 + 2] * Tp + wp[pc4 - 2] * Tm);
    Tp *= T; Tm *= Ti;
    accv += G0 * 0.011108997f * (wp[pc4 + 3] * Tp + wp[pc4 - 3] * Tm);
    return accv;
}

// ---------------------------------------------------------------------------
// kAB: fused conv0 + act + partial conv1.  Per block (tile, 2-channel group):
//   - stage x (40x40, edge-clamped, *255) in LDS
//   - a0 = act(conv5(x)+b0) on extended 36x36 (centers edge-clamped ==
//     rep_pad semantics); a0 stays in LDS; g0 = act' (bf16) for interior.
//   - partial c1 = sum_cc f1_cc (*) a0_cc on 32x32, 2x2/thread.
// 2048 blocks = 8/CU (32 waves/CU) for latency hiding.
// ---------------------------------------------------------------------------
__global__ __launch_bounds__(256) void kAB(const float* __restrict__ x,
                                           const float* __restrict__ f0,
                                           const float* __restrict__ b0,
                                           const float* __restrict__ w0,
                                           const float* __restrict__ f1,
                                           float* __restrict__ c1p,
                                           __hip_bfloat16* __restrict__ g0out) {
    __shared__ float xs[XSD * XSD];          // 6.4 KB
    __shared__ float a0s[CG][TLH * TLH];     // 10.4 KB
    __shared__ float w0ps[CG][PNP];          // 0.6 KB

    const int tile = blockIdx.x;
    const int cgi  = blockIdx.y;
    const int cg   = cgi * CG;
    const int b    = tile >> 4;
    const int t    = tile & 15;
    const int h0   = (t >> 2) * TLS;
    const int w0p  = (t & 3) * TLS;
    const int tid  = threadIdx.x;

    for (int i = tid; i < XSD * XSD; i += 256) {
        int iy = i / XSD, ix = i - iy * XSD;
        int gy = min(max(h0 + iy - 4, 0), IH - 1);
        int gx = min(max(w0p + ix - 4, 0), IW - 1);
        xs[i] = x[((size_t)b * IH + gy) * IW + gx] * 255.0f;
    }
    for (int i = tid; i < CG * PNP; i += 256) {
        int cc = i / PNP, k = i - cc * PNP;
        float v = 0.0f;
        if (k >= 4 && k < 4 + PN) v = w0[(size_t)(cg + cc) * PN + (k - 4)];
        w0ps[cc][k] = v;
    }
    __syncthreads();

    // a0 / g0 on extended region (window hoisted across the 2 channels)
    for (int p = tid; p < TLH * TLH; p += 256) {
        const int py = p / TLH, px = p - py * TLH;
        const int gy = h0 + py - 2, gx = w0p + px - 2;
        const int gyc = min(max(gy, 0), IH - 1);
        const int gxc = min(max(gx, 0), IW - 1);
        const bool interior = (gy == gyc) && (gx == gxc);
        const int cy = gyc - h0 + 4, cx = gxc - w0p + 4;

        float win[25];
#pragma unroll
        for (int u = 0; u < 5; ++u)
#pragma unroll
            for (int v = 0; v < 5; ++v)
                win[u * 5 + v] = xs[(cy - 2 + u) * XSD + cx - 2 + v];

#pragma unroll
        for (int cc = 0; cc < CG; ++cc) {
            const int c = cg + cc;
            float acc = b0[c];
#pragma unroll
            for (int k = 0; k < 25; ++k)
                acc = __fmaf_rn(win[k], f0[(size_t)c * 25 + k], acc);
            float av, ag;
            act_vg(acc, w0ps[cc], av, ag);
            a0s[cc][p] = av;
            if (interior)
                g0out[(((size_t)b * CH + c) * IH + gy) * IW + gx] = __float2bfloat16(ag);
        }
    }
    __syncthreads();

    // partial c1 (2x2 outputs per thread)
    const int lx = tid & 15, ly = tid >> 4;
    const int r0 = 2 * ly, c0 = 2 * lx;
    float a00 = 0.f, a01 = 0.f, a10 = 0.f, a11 = 0.f;

#pragma unroll
    for (int cc = 0; cc < CG; ++cc) {
        float win[6][6];
#pragma unroll
        for (int r = 0; r < 6; ++r) {
            const float2* rp = (const float2*)&a0s[cc][(r0 + r) * TLH + c0];
            float2 p0 = rp[0], p1 = rp[1], p2 = rp[2];
            win[r][0] = p0.x; win[r][1] = p0.y; win[r][2] = p1.x;
            win[r][3] = p1.y; win[r][4] = p2.x; win[r][5] = p2.y;
        }
#pragma unroll
        for (int u = 0; u < 5; ++u)
#pragma unroll
            for (int v = 0; v < 5; ++v) {
                const float kv = f1[(size_t)(cg + cc) * 25 + u * 5 + v];
                a00 = __fmaf_rn(win[u][v],         kv, a00);
                a01 = __fmaf_rn(win[u][v + 1],     kv, a01);
                a10 = __fmaf_rn(win[u + 1][v],     kv, a10);
                a11 = __fmaf_rn(win[u + 1][v + 1], kv, a11);
            }
    }

    const int oy = h0 + r0, ox = w0p + c0;
    const size_t base = (size_t)cgi * NPIX + ((size_t)b * IH + oy) * IW + ox;
    *(float2*)&c1p[base]      = make_float2(a00, a01);
    *(float2*)&c1p[base + IW] = make_float2(a10, a11);
}

// ---------------------------------------------------------------------------
// kB2: a1 = act(b1 + sum of 32 c1p partials, w1)
// ---------------------------------------------------------------------------
__global__ __launch_bounds__(256) void kB2(const float* __restrict__ c1p,
                                           const float* __restrict__ b1,
                                           const float* __restrict__ w1,
                                           float* __restrict__ a1) {
    __shared__ float w1p[PNP];
    const int tid = threadIdx.x;
    if (tid < PNP) {
        float v = 0.0f;
        if (tid >= 4 && tid < 4 + PN) v = w1[tid - 4];
        w1p[tid] = v;
    }
    __syncthreads();

    const int pid = blockIdx.x * 256 + tid;
    float vv = b1[0];
#pragma unroll
    for (int g = 0; g < NG; ++g) vv += c1p[(size_t)g * NPIX + pid];
    a1[pid] = act_v(vv, w1p);
}

// ---------------------------------------------------------------------------
// kCD: per block (tile, 2-channel group):
//   - stage a1 (40x40, zero outside image) in LDS
//   - dbuf_cc = conv_t5(a1) * g0 on 36x36 into LDS (window hoisted over cc)
//   - partial d3 = sum_cc f0_cc full-corr dbuf_cc on 32x32, 2x2/thread.
// ---------------------------------------------------------------------------
__global__ __launch_bounds__(256) void kCD(const float* __restrict__ a1,
                                           const float* __restrict__ f1,
                                           const float* __restrict__ f0,
                                           const __hip_bfloat16* __restrict__ g0,
                                           float* __restrict__ d3p) {
    __shared__ float a1s[XSD * XSD];         // 6.4 KB
    __shared__ float dbs[CG][TLH * TLH];     // 10.4 KB

    const int tile = blockIdx.x;
    const int cgi  = blockIdx.y;
    const int cg   = cgi * CG;
    const int b    = tile >> 4;
    const int t    = tile & 15;
    const int h0   = (t >> 2) * TLS;
    const int w0p  = (t & 3) * TLS;
    const int tid  = threadIdx.x;

    for (int p = tid; p < XSD * XSD; p += 256) {
        int iy = p / XSD, ix = p - iy * XSD;
        int gy = h0 + iy - 4, gx = w0p + ix - 4;
        float v = 0.0f;
        if ((unsigned)gy < IH && (unsigned)gx < IW)
            v = a1[((size_t)b * IH + gy) * IW + gx];
        a1s[p] = v;
    }
    __syncthreads();

    for (int p = tid; p < TLH * TLH; p += 256) {
        const int py = p / TLH, px = p - py * TLH;
        const int gy = h0 + py - 2, gx = w0p + px - 2;
        const bool inb = ((unsigned)gy < IH) && ((unsigned)gx < IW);

        float win[25];
#pragma unroll
        for (int u = 0; u < 5; ++u)
#pragma unroll
            for (int v = 0; v < 5; ++v)
                win[u * 5 + v] = a1s[(py + 4 - u) * XSD + (px + 4 - v)];

#pragma unroll
        for (int cc = 0; cc < CG; ++cc) {
            float out = 0.0f;
            if (inb) {
                const int c = cg + cc;
                float d1 = 0.0f;
#pragma unroll
                for (int k = 0; k < 25; ++k)
                    d1 = __fmaf_rn(win[k], f1[(size_t)c * 25 + k], d1);
                out = d1 * __bfloat162float(g0[(((size_t)b * CH + c) * IH + gy) * IW + gx]);
            }
            dbs[cc][p] = out;
        }
    }
    __syncthreads();

    const int lx = tid & 15, ly = tid >> 4;
    const int r0 = 2 * ly, c0 = 2 * lx;
    float a00 = 0.f, a01 = 0.f, a10 = 0.f, a11 = 0.f;

#pragma unroll
    for (int cc = 0; cc < CG; ++cc) {
        float win[6][6];
#pragma unroll
        for (int r = 0; r < 6; ++r) {
            const float2* rp = (const float2*)&dbs[cc][(r0 + r) * TLH + c0];
            float2 p0 = rp[0], p1 = rp[1], p2 = rp[2];
            win[r][0] = p0.x; win[r][1] = p0.y; win[r][2] = p1.x;
            win[r][3] = p1.y; win[r][4] = p2.x; win[r][5] = p2.y;
        }
#pragma unroll
        for (int u = 0; u < 5; ++u)
#pragma unroll
            for (int v = 0; v < 5; ++v) {
                const float kv = f0[(size_t)(cg + cc) * 25 + u * 5 + v];
                a00 = __fmaf_rn(win[4 - u][4 - v], kv, a00);
                a01 = __fmaf_rn(win[4 - u][5 - v], kv, a01);
                a10 = __fmaf_rn(win[5 - u][4 - v], kv, a10);
                a11 = __fmaf_rn(win[5 - u][5 - v], kv, a11);
            }
    }

    const int oy = h0 + r0, ox = w0p + c0;
    const size_t base = (size_t)cgi * NPIX + ((size_t)b * IH + oy) * IW + ox;
    *(float2*)&d3p[base]      = make_float2(a00, a01);
    *(float2*)&d3p[base + IW] = make_float2(a10, a11);
}

// ---------------------------------------------------------------------------
// kE: out = x - (sum of 32 d3 partials)/255 - exp(lam)*(x-y)
// ---------------------------------------------------------------------------
__global__ __launch_bounds__(256) void kE(const float* __restrict__ d3p,
                                          const float* __restrict__ x,
                                          const float* __restrict__ y,
                                          const float* __restrict__ lam_param,
                                          float* __restrict__ out) {
    const int pid = blockIdx.x * 256 + threadIdx.x;
    float d3 = 0.0f;
#pragma unroll
    for (int g = 0; g < NG; ++g) d3 += d3p[(size_t)g * NPIX + pid];
    const float elam = __expf(lam_param[0]);
    const float xv = x[pid], yv = y[pid];
    out[pid] = xv - d3 * (1.0f / 255.0f) - elam * (xv - yv);
}

// ---------------------------------------------------------------------------
extern "C" void kernel_launch(void* const* d_in, const int* in_sizes, int n_in,
                              void* d_out, int out_size, void* d_ws, size_t ws_size,
                              hipStream_t stream) {
    const float* x   = (const float*)d_in[0];
    const float* y   = (const float*)d_in[1];
    // d_in[2] = lam (ignored by reference)
    const float* f0  = (const float*)d_in[3];
    const float* b0  = (const float*)d_in[4];
    const float* f1  = (const float*)d_in[5];
    const float* b1  = (const float*)d_in[6];
    const float* w0  = (const float*)d_in[7];
    const float* w1  = (const float*)d_in[8];
    const float* lam = (const float*)d_in[9];
    float* out = (float*)d_out;

    const size_t nch = (size_t)BSZ * CH * IH * IW;   // 4.19M elements
    __hip_bfloat16* g0 = (__hip_bfloat16*)d_ws;      // 8.4 MB (bf16)
    float* a1  = (float*)(g0 + nch);                 // 0.26 MB
    float* c1p = a1 + NPIX;                          // NG * NPIX (8.4 MB)
    float* d3p = c1p + (size_t)NG * NPIX;            // NG * NPIX (8.4 MB)

    kAB<<<dim3(NT, NG), 256, 0, stream>>>(x, f0, b0, w0, f1, c1p, g0);
    kB2<<<NPIX / 256, 256, 0, stream>>>(c1p, b1, w1, a1);
    kCD<<<dim3(NT, NG), 256, 0, stream>>>(a1, f1, f0, g0, d3p);
    kE <<<NPIX / 256, 256, 0, stream>>>(d3p, x, y, lam, out);
}